// Round 10
// baseline (135.386 us; speedup 1.0000x reference)
//
#include <hip/hip_runtime.h>

#define CDIM 64
#define TDIM 24
#define NDIM 512
#define NBT  192   // B*T = 8*24

typedef float    float4v __attribute__((ext_vector_type(4)));
typedef _Float16 half8v  __attribute__((ext_vector_type(8)));
typedef _Float16 half4v  __attribute__((ext_vector_type(4)));
typedef _Float16 half2v  __attribute__((ext_vector_type(2)));

// ---------------------------------------------------------------------------
// Workspace layout (bytes):
//   VT_g   : _Float16 [NBT][4][1024][8]  0        (12582912 B)
//            FRAGMENT ORDER: [bt][js][h*8+ksl*2+b][lane] x 16B — k2's LDS
//            prefetch/commit/read are all lane-linear (bank-optimal, R9).
//   s_src  : float    [NBT][2][512]    12582912   (786432 B)   (exp2 domain)
//   s_dst  : float    [NBT][2][512]    13369344   (786432 B)   (exp2 domain)
//   maskb  : u8       [512][512]       14155776   (262144 B)   {0x00,0xFF}
// Session ledger: fills ~88 us/iter (immovable); k1 ~1.5; k2 ~28-30 with ALL
// pipes <20% busy (R8 PMC) -> latency-bound at 12 waves/CU (grid 768 = 3
// blocks/CU was the occupancy cap, not __launch_bounds__). This round:
// ROWBLK=64 -> 1536 blocks (6/CU), lean 21.5 KB LDS, (256,5) bounds ->
// ~20 waves/CU (+67% latency cover), with R9's conflict-free fragment vt.
// ---------------------------------------------------------------------------

__device__ __forceinline__ float exp2_fast(float x) {
#if __has_builtin(__builtin_amdgcn_exp2f)
  return __builtin_amdgcn_exp2f(x);
#else
  return __expf(x * 0.69314718f);
#endif
}

// ======== kernel 1: V = X @ Wv^T (f16 MFMA) + score cols + mask pack ========
// 1D grid, 832 blocks:
//   blocks 0..767  : compute; qn = bx & 3 (node quarter = k2's js), bt = bx >> 2
//   blocks 768..831: gso -> byte-mask pack (pure BW, overlaps compute blocks)
struct SmemK1 {
  union {
    _Float16 xt[128][72];    // X tile [node][c], 144 B rows
    _Float16 vtb[64][136];   // V^T bounce [c][node]
  } big;                     // 18432 B
  _Float16 wv[64][72];       // Wv [d][k]             9216 B
  _Float16 wext[16][72];     // rows 0..3 = log2e * (a_h^T W_h), rest 0   2304 B
};                            // 29952 B

__launch_bounds__(256, 4)
__global__ void k1_v(const float* __restrict__ x,  const float* __restrict__ Wv,
                     const float* __restrict__ Wq, const float* __restrict__ Wk,
                     const float* __restrict__ a_src, const float* __restrict__ a_dst,
                     const int* __restrict__ gso,
                     _Float16* __restrict__ VT_g,
                     float* __restrict__ s_src_g, float* __restrict__ s_dst_g,
                     unsigned char* __restrict__ maskb) {
  const int t  = threadIdx.x;
  const int bx = blockIdx.x;

  if (bx >= 768) {   // ---- mask-pack blocks: 16 ints -> 16 mask bytes each ----
    int g = (bx - 768) * 256 + t;            // 0..16383
    const int4* gp = (const int4*)gso + (size_t)g * 4;
    unsigned w[4];
#pragma unroll
    for (int k = 0; k < 4; ++k) {
      int4 v = gp[k];
      w[k] = (v.x ? 0x000000FFu : 0u) | (v.y ? 0x0000FF00u : 0u) |
             (v.z ? 0x00FF0000u : 0u) | (v.w ? 0xFF000000u : 0u);
    }
    uint4 o; o.x = w[0]; o.y = w[1]; o.z = w[2]; o.w = w[3];
    ((uint4*)maskb)[g] = o;
    return;
  }

  __shared__ SmemK1 sm;
  const int qn = bx & 3;
  const int bt = bx >> 2;
  const int b  = bt / TDIM, tt = bt % TDIM;
  const int n0 = qn * 128;

  // stage Wv -> f16 LDS (dwordx4 loads)
#pragma unroll
  for (int it = 0; it < 4; ++it) {
    int idx = it * 256 + t;                 // 0..1023 float4s
    float4 vv = ((const float4*)Wv)[idx];
    int d = idx >> 4, k4 = (idx & 15) * 4;
    half4v h4; h4[0] = (_Float16)vv.x; h4[1] = (_Float16)vv.y;
    h4[2] = (_Float16)vv.z; h4[3] = (_Float16)vv.w;
    *(half4v*)&sm.wv[d][k4] = h4;
  }
  // wext: zero rows 4..15; rows 0..3 = log2e * (a_h^T W_h)  (exp2 domain)
  for (int z = t; z < 12 * 72; z += 256) ((_Float16*)sm.wext[4])[z] = (_Float16)0.f;
  if (t < 64) {
    int c = t;
    float s0 = 0.f, s1 = 0.f, d0 = 0.f, d1 = 0.f;
#pragma unroll
    for (int d = 0; d < 32; ++d) {
      s0 += a_src[d]      * Wq[d * 64 + c];
      s1 += a_src[32 + d] * Wq[(32 + d) * 64 + c];
      d0 += a_dst[d]      * Wk[d * 64 + c];
      d1 += a_dst[32 + d] * Wk[(32 + d) * 64 + c];
    }
    const float l2e = 1.44269504f;
    sm.wext[0][c] = (_Float16)(s0 * l2e); sm.wext[1][c] = (_Float16)(s1 * l2e);
    sm.wext[2][c] = (_Float16)(d0 * l2e); sm.wext[3][c] = (_Float16)(d1 * l2e);
  }
  // stage X tile (channel pairs -> half2)
  for (int it = 0; it < 16; ++it) {
    int idx = it * 256 + t;
    int cp = idx >> 7, n = idx & 127;
    int c0 = cp * 2;
    const float* base = x + ((size_t)(b * CDIM + c0) * TDIM + tt) * NDIM + n0 + n;
    half2v p; p[0] = (_Float16)base[0]; p[1] = (_Float16)base[(size_t)TDIM * NDIM];
    *(half2v*)&sm.big.xt[n][c0] = p;
  }
  __syncthreads();

  const int lane = t & 63, w = t >> 6;
  const int m = lane & 15, quad = lane >> 4;
  const int mbase = w * 32;   // 32 nodes per wave

  float4v acc[2][5];
#pragma unroll
  for (int mt = 0; mt < 2; ++mt)
#pragma unroll
    for (int nt = 0; nt < 5; ++nt)
#pragma unroll
      for (int r = 0; r < 4; ++r) acc[mt][nt][r] = 0.f;

#pragma unroll
  for (int ks = 0; ks < 2; ++ks) {
    half8v af[2], bf[5];
#pragma unroll
    for (int mt = 0; mt < 2; ++mt)
      af[mt] = *(const half8v*)&sm.big.xt[mbase + mt * 16 + m][ks * 32 + quad * 8];
#pragma unroll
    for (int nt = 0; nt < 4; ++nt)
      bf[nt] = *(const half8v*)&sm.wv[nt * 16 + m][ks * 32 + quad * 8];
    bf[4] = *(const half8v*)&sm.wext[m][ks * 32 + quad * 8];
#pragma unroll
    for (int mt = 0; mt < 2; ++mt)
#pragma unroll
      for (int nt = 0; nt < 5; ++nt)
        acc[mt][nt] = __builtin_amdgcn_mfma_f32_16x16x32_f16(af[mt], bf[nt], acc[mt][nt], 0, 0, 0);
  }

  // scatter score columns (col 0/1 = ssrc h0/h1, col 2/3 = sdst h0/h1)
  if (m < 4) {
    float* basep = (m < 2 ? s_src_g : s_dst_g) + (size_t)(bt * 2 + (m & 1)) * NDIM;
#pragma unroll
    for (int mt = 0; mt < 2; ++mt)
#pragma unroll
      for (int r = 0; r < 4; ++r)
        basep[n0 + mbase + mt * 16 + quad * 4 + r] = acc[mt][4][r];
  }
  __syncthreads();   // xt fully consumed before overlay

  // V^T bounce into LDS (pack node pairs)
#pragma unroll
  for (int mt = 0; mt < 2; ++mt)
#pragma unroll
    for (int nt = 0; nt < 4; ++nt)
#pragma unroll
      for (int r = 0; r < 4; r += 2) {
        int nl = mbase + mt * 16 + quad * 4 + r;
        int c  = nt * 16 + m;
        half2v p = __builtin_bit_cast(half2v,
            __builtin_amdgcn_cvt_pkrtz(acc[mt][nt][r], acc[mt][nt][r + 1]));
        *(half2v*)&sm.big.vtb[c][nl] = p;
      }
  __syncthreads();

  // fragment-ordered V^T -> global (coalesced 16B/thread x 4):
  // frag f = (fh, fksl, fb, flane): c = fh*32 + fb*16 + (flane&15),
  // jq = fksl*32 + (flane>>4)*8 (halfs within this 128-node quarter)
  const _Float16* vtbf = (const _Float16*)sm.big.vtb;   // row stride 136 halfs
#pragma unroll
  for (int it = 0; it < 4; ++it) {
    int f    = it * 256 + t;            // 0..1023
    int fh   = f >> 9;
    int fksl = (f >> 7) & 3;
    int fb   = (f >> 6) & 1;
    int fl   = f & 63;
    int c  = fh * 32 + fb * 16 + (fl & 15);
    int jq = fksl * 32 + (fl >> 4) * 8;
    uint4 v = *(const uint4*)(vtbf + c * 136 + jq);
    ((uint4*)VT_g)[((size_t)bt * 4 + qn) * 1024 + f] = v;
  }
}

// ======== kernel 2: masked softmax(P) @ V + LayerNorm + transpose ===========
// ROWBLK=64: 8 i-tiles x 192 bt = 1536 blocks -> 6 blocks/CU available
// (occupancy was the binder: 768-block grid pinned us to 12 waves/CU with
// every pipe <20% busy). XCD swizzle: id = (bt&7) + 8*itile + 64*(bt>>3);
// the 8 blocks sharing one 64 KB VT panel land on one XCD's L2.
// e_ij = max(E_i*F_j, Q_i*P_j), packed-f16 half2 ops. Masks direct from
// global (L2-hot). VT in FRAGMENT ORDER (R9): prefetch/commit/read all
// lane-linear, zero bank conflicts. Lean LDS (21.5 KB union) + (256,5)
// bounds -> ~5 blocks/CU resident, ~20 waves/CU.
struct SmemK2 {
  union {
    struct { _Float16 vt[8192];                 // 16384
             _Float16 sF16[2][512];             // 2048  F_j  = 2^{d'_j}
             _Float16 sP16[2][512]; } s;        // 2048  -> 20480 B
    struct { float otile[64][66]; float rsum[4][64]; float rsq[4][64];
             float mu[64]; float rs[64]; } e;   // 21504 B
  } u;
};                          // 21504 B -> LDS allows 7/CU; VGPR(5w) caps ~5

__launch_bounds__(256, 5)
__global__ void k2_attn(const _Float16* __restrict__ VT_g,
                        const float* __restrict__ s_src_g, const float* __restrict__ s_dst_g,
                        const unsigned char* __restrict__ maskb,
                        const float* __restrict__ gamma, const float* __restrict__ beta,
                        float* __restrict__ out) {
  __shared__ SmemK2 sm;
  const int t     = threadIdx.x;
  const int id    = blockIdx.x;
  const int itile = (id >> 3) & 7;
  const int bt    = ((id >> 6) << 3) | (id & 7);
  const int i0    = itile * 64;
  const int b     = bt / TDIM, tt = bt % TDIM;
  const int lane  = t & 63, w = t >> 6;
  const int h = w >> 1, ihalf = w & 1;
  const int m = lane & 15, quad = lane >> 4;
  const int rbase = ihalf * 32;    // this wave's 32-row half of the 64-row tile

  // stage F/Fp as f16 (1024 exp2 pairs per block)
  for (int it = 0; it < 4; ++it) {
    int idx = it * 256 + t;
    float d = s_dst_g[(size_t)bt * 2 * NDIM + idx];
    ((_Float16*)sm.u.s.sF16)[idx] = (_Float16)exp2_fast(d);
    ((_Float16*)sm.u.s.sP16)[idx] = (_Float16)exp2_fast(0.2f * d);
  }
  // per-row source factors as packed half2 (bias -6 keeps products f16-normal)
  half2v e2[2], q2[2];
#pragma unroll
  for (int mt = 0; mt < 2; ++mt) {
    float sv = s_src_g[(size_t)(bt * 2 + h) * NDIM + i0 + rbase + mt * 16 + m];
    _Float16 ev = (_Float16)exp2_fast(sv - 6.f);
    _Float16 qv = (_Float16)exp2_fast(0.2f * sv - 6.f);
    e2[mt][0] = ev; e2[mt][1] = ev;
    q2[mt][0] = qv; q2[mt][1] = qv;
  }

  float4v acc[2][2], accs[2];
#pragma unroll
  for (int mt = 0; mt < 2; ++mt)
#pragma unroll
    for (int r = 0; r < 4; ++r) { acc[mt][0][r] = 0.f; acc[mt][1][r] = 0.f; accs[mt][r] = 0.f; }
  const half8v bones = {(_Float16)1.f, (_Float16)1.f, (_Float16)1.f, (_Float16)1.f,
                        (_Float16)1.f, (_Float16)1.f, (_Float16)1.f, (_Float16)1.f};

  // ---- VT register prefetch: FOUR NAMED uint4 scalars (linear slots) ----
  const uint4* vsrc = (const uint4*)VT_g;
  uint4 pv0, pv1, pv2, pv3;

  // per-lane mask row base: rows i0 + rbase + mt*16 + m  (L2-hot)
  const unsigned char* mrow = maskb + (size_t)(i0 + rbase + m) * NDIM + quad * 8;

#define PREFETCH_V(js_)                                                        \
  { size_t vb = ((size_t)bt * 4 + (js_)) * 1024 + t;                           \
    pv0 = vsrc[vb];       pv1 = vsrc[vb + 256];                                \
    pv2 = vsrc[vb + 512]; pv3 = vsrc[vb + 768]; }

#define SLICE(js_, ksl_)                                                       \
  {                                                                            \
    const int jq = (ksl_) * 32 + quad * 8;                                     \
    half8v F8 = *(const half8v*)&sm.u.s.sF16[h][(js_) * 128 + jq];             \
    half8v P8 = *(const half8v*)&sm.u.s.sP16[h][(js_) * 128 + jq];             \
    const int fs = ((h * 8 + (ksl_) * 2) * 64 + lane) * 8;                     \
    half8v b0 = *(const half8v*)&sm.u.s.vt[fs];                                \
    half8v b1 = *(const half8v*)&sm.u.s.vt[fs + 512];                          \
    uint4 fu = __builtin_bit_cast(uint4, F8);                                  \
    uint4 pu = __builtin_bit_cast(uint4, P8);                                  \
    half2v f2a = __builtin_bit_cast(half2v, fu.x), f2b = __builtin_bit_cast(half2v, fu.y); \
    half2v f2c = __builtin_bit_cast(half2v, fu.z), f2d = __builtin_bit_cast(half2v, fu.w); \
    half2v p2a = __builtin_bit_cast(half2v, pu.x), p2b = __builtin_bit_cast(half2v, pu.y); \
    half2v p2c = __builtin_bit_cast(half2v, pu.z), p2d = __builtin_bit_cast(half2v, pu.w); \
    _Pragma("unroll")                                                          \
    for (int mt = 0; mt < 2; ++mt) {                                           \
      unsigned mw0 = mk[mt][ksl_].x, mw1 = mk[mt][ksl_].y;                     \
      uint4 eu;                                                                \
      eu.x = __builtin_bit_cast(unsigned,                                      \
               __builtin_elementwise_max(e2[mt] * f2a, q2[mt] * p2a)) &        \
             __builtin_amdgcn_perm(0u, mw0, 0x01010000u);                      \
      eu.y = __builtin_bit_cast(unsigned,                                      \
               __builtin_elementwise_max(e2[mt] * f2b, q2[mt] * p2b)) &        \
             __builtin_amdgcn_perm(0u, mw0, 0x03030202u);                      \
      eu.z = __builtin_bit_cast(unsigned,                                      \
               __builtin_elementwise_max(e2[mt] * f2c, q2[mt] * p2c)) &        \
             __builtin_amdgcn_perm(0u, mw1, 0x01010000u);                      \
      eu.w = __builtin_bit_cast(unsigned,                                      \
               __builtin_elementwise_max(e2[mt] * f2d, q2[mt] * p2d)) &        \
             __builtin_amdgcn_perm(0u, mw1, 0x03030202u);                      \
      half8v af = __builtin_bit_cast(half8v, eu);                              \
      acc[mt][0] = __builtin_amdgcn_mfma_f32_16x16x32_f16(af, b0,    acc[mt][0], 0, 0, 0); \
      acc[mt][1] = __builtin_amdgcn_mfma_f32_16x16x32_f16(af, b1,    acc[mt][1], 0, 0, 0); \
      accs[mt]   = __builtin_amdgcn_mfma_f32_16x16x32_f16(af, bones, accs[mt],   0, 0, 0); \
    }                                                                          \
  }

  PREFETCH_V(0);

#pragma unroll
  for (int js = 0; js < 4; ++js) {
    __syncthreads();   // prev quarter fully consumed
    // commit prefetched VT quarter to LDS (lane-linear 16B slots)
    ((uint4*)sm.u.s.vt)[t      ] = pv0;
    ((uint4*)sm.u.s.vt)[t + 256] = pv1;
    ((uint4*)sm.u.s.vt)[t + 512] = pv2;
    ((uint4*)sm.u.s.vt)[t + 768] = pv3;
    __syncthreads();
    if (js < 3) PREFETCH_V(js + 1);   // latency hides under this quarter's compute

    // mask bytes for this quarter: 8 x uint2 per lane
    uint2 mk[2][4];
#pragma unroll
    for (int mt = 0; mt < 2; ++mt) {
      const unsigned char* mbp = mrow + (size_t)(mt * 16) * NDIM + js * 128;
#pragma unroll
      for (int ksl = 0; ksl < 4; ++ksl)
        mk[mt][ksl] = *(const uint2*)(mbp + ksl * 32);
    }

    SLICE(js, 0);
    SLICE(js, 1);
    SLICE(js, 2);
    SLICE(js, 3);
  }
#undef SLICE
#undef PREFETCH_V

  __syncthreads();   // vt/F/P dead -> otile overlay
  // normalize by row sums (same C-layout row as acc -> no shuffle needed)
#pragma unroll
  for (int mt = 0; mt < 2; ++mt)
#pragma unroll
    for (int r = 0; r < 4; ++r) {
      float sc = __builtin_amdgcn_rcpf(accs[mt][r]);
      int i_loc = rbase + mt * 16 + quad * 4 + r;
#pragma unroll
      for (int nt = 0; nt < 2; ++nt)
        sm.u.e.otile[i_loc][h * 32 + nt * 16 + m] = acc[mt][nt][r] * sc;
    }
  __syncthreads();

  // LayerNorm over C=64 per row (64 rows, 4 threads/row x 16 ch)
  {
    int i = t & 63, cg = t >> 6;
    float s1 = 0.f, s2 = 0.f;
#pragma unroll
    for (int cc = 0; cc < 16; ++cc) {
      float v = sm.u.e.otile[i][cg * 16 + cc];
      s1 += v; s2 += v * v;
    }
    sm.u.e.rsum[cg][i] = s1;
    sm.u.e.rsq[cg][i]  = s2;
  }
  __syncthreads();
  if (t < 64) {
    int i = t;
    float s1 = 0.f, s2 = 0.f;
#pragma unroll
    for (int cg = 0; cg < 4; ++cg) { s1 += sm.u.e.rsum[cg][i]; s2 += sm.u.e.rsq[cg][i]; }
    float mu  = s1 * (1.f / 64.f);
    float var = s2 * (1.f / 64.f) - mu * mu;
    sm.u.e.mu[i] = mu;
    sm.u.e.rs[i] = rsqrtf(var + 1e-5f);
  }
  __syncthreads();
  {
    int i = t & 63, cg = t >> 6;
    float mu = sm.u.e.mu[i], rs = sm.u.e.rs[i];
    int n = i0 + i;
#pragma unroll
    for (int cc = 0; cc < 16; ++cc) {
      int c = cg * 16 + cc;
      float v = (sm.u.e.otile[i][c] - mu) * rs * gamma[c] + beta[c];
      out[((size_t)(b * CDIM + c) * TDIM + tt) * NDIM + n] = v;
    }
  }
}

// ---------------------------------------------------------------------------
extern "C" void kernel_launch(void* const* d_in, const int* in_sizes, int n_in,
                              void* d_out, int out_size, void* d_ws, size_t ws_size,
                              hipStream_t stream) {
  const float* x     = (const float*)d_in[0];
  const int*   gso   = (const int*)d_in[1];
  const float* Wq    = (const float*)d_in[2];
  const float* Wk    = (const float*)d_in[3];
  const float* Wv    = (const float*)d_in[4];
  const float* a_src = (const float*)d_in[5];
  const float* a_dst = (const float*)d_in[6];
  const float* gamma = (const float*)d_in[7];
  const float* beta  = (const float*)d_in[8];
  float* out = (float*)d_out;

  char* ws = (char*)d_ws;
  _Float16* VT_g  = (_Float16*)ws;
  float*    s_src = (float*)(ws + 12582912);
  float*    s_dst = (float*)(ws + 13369344);
  unsigned char* maskb = (unsigned char*)(ws + 14155776);

  k1_v<<<832, 256, 0, stream>>>(x, Wv, Wq, Wk, a_src, a_dst, gso,
                                VT_g, s_src, s_dst, maskb);
  k2_attn<<<1536, 256, 0, stream>>>(VT_g, s_src, s_dst, maskb, gamma, beta, out);
}

// Round 11
// 121.590 us; speedup vs baseline: 1.1135x; 1.1135x over previous
//
#include <hip/hip_runtime.h>

#define CDIM 64
#define TDIM 24
#define NDIM 512
#define NBT  192   // B*T = 8*24

typedef float    float4v __attribute__((ext_vector_type(4)));
typedef _Float16 half8v  __attribute__((ext_vector_type(8)));
typedef _Float16 half4v  __attribute__((ext_vector_type(4)));
typedef _Float16 half2v  __attribute__((ext_vector_type(2)));

// ---------------------------------------------------------------------------
// EXACT REVERT to the Round-4 kernel — session best (121.9 us measured).
// Workspace layout (bytes):
//   VT_g   : _Float16 [NBT][64][512]   0          (12582912 B)
//   s_src  : float    [NBT][2][512]    12582912   (786432 B)   (exp2 domain)
//   s_dst  : float    [NBT][2][512]    13369344   (786432 B)   (exp2 domain)
//   maskb  : u8       [512][512]       14155776   (262144 B)   {0x00,0xFF}
// Session ledger (10 rounds): wall = fills ~88 us (2x256MiB re-poison,
// immovable) + k1 ~1.5 + k2 ~28 + gaps. Six mechanism-distinct attacks on
// k2's latency plateau all flat-to-negative:
//   R5 occupancy-bounds (impossible: grid-capped), R6 dbuf/1-barrier (flat),
//   R7 zero-barrier direct-global VT (-7: staging earns its keep),
//   R8 mask reg-dbuf (compiler sank it), R9 fragment-order vt (conflicts
//   weren't the path), R10 2x grid (-13: occupancy pinned ~30% regardless;
//   per-block staging fraction doubled).
// k2 runs all pipes <20% busy at ~10-12 waves/CU in every config — a
// latency plateau this schedule family cannot break at HIP source level.
// ---------------------------------------------------------------------------

__device__ __forceinline__ float exp2_fast(float x) {
#if __has_builtin(__builtin_amdgcn_exp2f)
  return __builtin_amdgcn_exp2f(x);
#else
  return __expf(x * 0.69314718f);
#endif
}

// ======== kernel 1: V = X @ Wv^T (f16 MFMA) + score cols + mask pack ========
// 1D grid, 832 blocks:
//   blocks 0..767  : compute; qn = bx & 3 (node quarter), bt = bx >> 2
//   blocks 768..831: gso -> byte-mask pack (pure BW, overlaps compute blocks)
struct SmemK1 {
  union {
    _Float16 xt[128][72];    // X tile [node][c], 144 B rows
    _Float16 vtb[64][136];   // V^T bounce [c][node]
  } big;                     // 18432 B
  _Float16 wv[64][72];       // Wv [d][k]             9216 B
  _Float16 wext[16][72];     // rows 0..3 = log2e * (a_h^T W_h), rest 0   2304 B
};                            // 29952 B

__launch_bounds__(256, 4)
__global__ void k1_v(const float* __restrict__ x,  const float* __restrict__ Wv,
                     const float* __restrict__ Wq, const float* __restrict__ Wk,
                     const float* __restrict__ a_src, const float* __restrict__ a_dst,
                     const int* __restrict__ gso,
                     _Float16* __restrict__ VT_g,
                     float* __restrict__ s_src_g, float* __restrict__ s_dst_g,
                     unsigned char* __restrict__ maskb) {
  const int t  = threadIdx.x;
  const int bx = blockIdx.x;

  if (bx >= 768) {   // ---- mask-pack blocks: 16 ints -> 16 mask bytes each ----
    int g = (bx - 768) * 256 + t;            // 0..16383
    const int4* gp = (const int4*)gso + (size_t)g * 4;
    unsigned w[4];
#pragma unroll
    for (int k = 0; k < 4; ++k) {
      int4 v = gp[k];
      w[k] = (v.x ? 0x000000FFu : 0u) | (v.y ? 0x0000FF00u : 0u) |
             (v.z ? 0x00FF0000u : 0u) | (v.w ? 0xFF000000u : 0u);
    }
    uint4 o; o.x = w[0]; o.y = w[1]; o.z = w[2]; o.w = w[3];
    ((uint4*)maskb)[g] = o;
    return;
  }

  __shared__ SmemK1 sm;
  const int qn = bx & 3;
  const int bt = bx >> 2;
  const int b  = bt / TDIM, tt = bt % TDIM;
  const int n0 = qn * 128;

  // stage Wv -> f16 LDS (dwordx4 loads, b64 LDS writes)
#pragma unroll
  for (int it = 0; it < 4; ++it) {
    int idx = it * 256 + t;                 // 0..1023 float4s
    float4 vv = ((const float4*)Wv)[idx];
    int d = idx >> 4, k4 = (idx & 15) * 4;
    half4v h4; h4[0] = (_Float16)vv.x; h4[1] = (_Float16)vv.y;
    h4[2] = (_Float16)vv.z; h4[3] = (_Float16)vv.w;
    *(half4v*)&sm.wv[d][k4] = h4;
  }
  // wext: zero rows 4..15; rows 0..3 = log2e * (a_h^T W_h)  (exp2 domain)
  for (int z = t; z < 12 * 72; z += 256) ((_Float16*)sm.wext[4])[z] = (_Float16)0.f;
  if (t < 64) {
    int c = t;
    float s0 = 0.f, s1 = 0.f, d0 = 0.f, d1 = 0.f;
#pragma unroll
    for (int d = 0; d < 32; ++d) {
      s0 += a_src[d]      * Wq[d * 64 + c];
      s1 += a_src[32 + d] * Wq[(32 + d) * 64 + c];
      d0 += a_dst[d]      * Wk[d * 64 + c];
      d1 += a_dst[32 + d] * Wk[(32 + d) * 64 + c];
    }
    const float l2e = 1.44269504f;
    sm.wext[0][c] = (_Float16)(s0 * l2e); sm.wext[1][c] = (_Float16)(s1 * l2e);
    sm.wext[2][c] = (_Float16)(d0 * l2e); sm.wext[3][c] = (_Float16)(d1 * l2e);
  }
  // stage X tile (channel pairs -> half2)
  for (int it = 0; it < 16; ++it) {
    int idx = it * 256 + t;
    int cp = idx >> 7, n = idx & 127;
    int c0 = cp * 2;
    const float* base = x + ((size_t)(b * CDIM + c0) * TDIM + tt) * NDIM + n0 + n;
    half2v p; p[0] = (_Float16)base[0]; p[1] = (_Float16)base[(size_t)TDIM * NDIM];
    *(half2v*)&sm.big.xt[n][c0] = p;
  }
  __syncthreads();

  const int lane = t & 63, w = t >> 6;
  const int m = lane & 15, quad = lane >> 4;
  const int mbase = w * 32;   // 32 nodes per wave

  float4v acc[2][5];
#pragma unroll
  for (int mt = 0; mt < 2; ++mt)
#pragma unroll
    for (int nt = 0; nt < 5; ++nt)
#pragma unroll
      for (int r = 0; r < 4; ++r) acc[mt][nt][r] = 0.f;

#pragma unroll
  for (int ks = 0; ks < 2; ++ks) {
    half8v af[2], bf[5];
#pragma unroll
    for (int mt = 0; mt < 2; ++mt)
      af[mt] = *(const half8v*)&sm.big.xt[mbase + mt * 16 + m][ks * 32 + quad * 8];
#pragma unroll
    for (int nt = 0; nt < 4; ++nt)
      bf[nt] = *(const half8v*)&sm.wv[nt * 16 + m][ks * 32 + quad * 8];
    bf[4] = *(const half8v*)&sm.wext[m][ks * 32 + quad * 8];
#pragma unroll
    for (int mt = 0; mt < 2; ++mt)
#pragma unroll
      for (int nt = 0; nt < 5; ++nt)
        acc[mt][nt] = __builtin_amdgcn_mfma_f32_16x16x32_f16(af[mt], bf[nt], acc[mt][nt], 0, 0, 0);
  }

  // scatter score columns (col 0/1 = ssrc h0/h1, col 2/3 = sdst h0/h1)
  if (m < 4) {
    float* basep = (m < 2 ? s_src_g : s_dst_g) + (size_t)(bt * 2 + (m & 1)) * NDIM;
#pragma unroll
    for (int mt = 0; mt < 2; ++mt)
#pragma unroll
      for (int r = 0; r < 4; ++r)
        basep[n0 + mbase + mt * 16 + quad * 4 + r] = acc[mt][4][r];
  }
  __syncthreads();   // xt fully consumed before overlay

  // V^T bounce into LDS (pack node pairs)
#pragma unroll
  for (int mt = 0; mt < 2; ++mt)
#pragma unroll
    for (int nt = 0; nt < 4; ++nt)
#pragma unroll
      for (int r = 0; r < 4; r += 2) {
        int nl = mbase + mt * 16 + quad * 4 + r;
        int c  = nt * 16 + m;
        half2v p = __builtin_bit_cast(half2v,
            __builtin_amdgcn_cvt_pkrtz(acc[mt][nt][r], acc[mt][nt][r + 1]));
        *(half2v*)&sm.big.vtb[c][nl] = p;
      }
  __syncthreads();

  // coalesced V^T -> global, dwordx4 (4 iters: 64 rows x 16 uint4)
  const uint4* vq = (const uint4*)sm.big.vtb;   // row stride 17 uint4 (272 B)
#pragma unroll
  for (int it = 0; it < 4; ++it) {
    int idx = it * 256 + t;                     // 0..1023
    int c = idx >> 4, q4 = idx & 15;
    ((uint4*)VT_g)[(size_t)(bt * 64 + c) * 64 + qn * 16 + q4] = vq[c * 17 + q4];
  }
}

// ======== kernel 2: masked softmax(P) @ V + LayerNorm + transpose ===========
// ROWBLK=128: 4 i-tiles x 192 bt = 768 blocks. F8/P8/b0/b1 LDS reads are
// shared across mt, so 2x rows/block halves LDS-read traffic per output,
// halves barriers, halves VT L2 re-reads. XCD swizzle:
//   id = (bt&7) + 8*itile + 32*(bt>>3); XCD ~ id%8 = bt%8 -> the 4 blocks
// sharing one VT panel land on one XCD's L2.
// e_ij = max(E_i*F_j, Q_i*P_j), packed-f16 half2 ops. Masks read directly
// from global (256 KB, L2-hot). VT prefetched into NAMED uint4 scalars;
// js loop fully unrolled (rule #20: all static indexing).
struct SmemK2 {
  union {
    struct { _Float16 vt[64][128]; } s;                              // 16384
    struct { float otile[128][66]; float rsum[2][128]; float rsq[2][128];
             float mu[128]; float rs[128]; } e;                      // 36864
  } u;
  _Float16 sF16[2][512];   // 2048  F_j  = 2^{d'_j}   (f16)
  _Float16 sP16[2][512];   // 2048  Fp_j = 2^{0.2 d'_j} (f16)
};                          // 40960 B -> 3 blocks/CU (grid = exactly 3/CU)

__launch_bounds__(256, 3)
__global__ void k2_attn(const _Float16* __restrict__ VT_g,
                        const float* __restrict__ s_src_g, const float* __restrict__ s_dst_g,
                        const unsigned char* __restrict__ maskb,
                        const float* __restrict__ gamma, const float* __restrict__ beta,
                        float* __restrict__ out) {
  __shared__ SmemK2 sm;
  const int t     = threadIdx.x;
  const int id    = blockIdx.x;
  const int itile = (id >> 3) & 3;
  const int bt    = ((id >> 5) << 3) | (id & 7);
  const int i0    = itile * 128;
  const int b     = bt / TDIM, tt = bt % TDIM;
  const int lane  = t & 63, w = t >> 6;
  const int h = w >> 1, ihalf = w & 1;
  const int m = lane & 15, quad = lane >> 4;
  const int rbase = ihalf * 64;    // this wave's 64-row half of the 128-row tile

  // stage F/Fp as f16 (1024 exp2 pairs per block)
  for (int it = 0; it < 4; ++it) {
    int idx = it * 256 + t;
    float d = s_dst_g[(size_t)bt * 2 * NDIM + idx];
    ((_Float16*)sm.sF16)[idx] = (_Float16)exp2_fast(d);
    ((_Float16*)sm.sP16)[idx] = (_Float16)exp2_fast(0.2f * d);
  }
  // per-row source factors as packed half2 (single reg each; bias -6 keeps
  // products f16-normal)
  half2v e2[4], q2[4];
#pragma unroll
  for (int mt = 0; mt < 4; ++mt) {
    float sv = s_src_g[(size_t)(bt * 2 + h) * NDIM + i0 + rbase + mt * 16 + m];
    _Float16 ev = (_Float16)exp2_fast(sv - 6.f);
    _Float16 qv = (_Float16)exp2_fast(0.2f * sv - 6.f);
    e2[mt][0] = ev; e2[mt][1] = ev;
    q2[mt][0] = qv; q2[mt][1] = qv;
  }

  float4v acc[4][2], accs[4];
#pragma unroll
  for (int mt = 0; mt < 4; ++mt)
#pragma unroll
    for (int r = 0; r < 4; ++r) { acc[mt][0][r] = 0.f; acc[mt][1][r] = 0.f; accs[mt][r] = 0.f; }
  const half8v bones = {(_Float16)1.f, (_Float16)1.f, (_Float16)1.f, (_Float16)1.f,
                        (_Float16)1.f, (_Float16)1.f, (_Float16)1.f, (_Float16)1.f};

  // ---- VT register prefetch state: FOUR NAMED uint4 scalars ----
  const uint4* vsrc = (const uint4*)VT_g;
  uint4 pv0, pv1, pv2, pv3;
  const int vc  = t >> 4;            // 0..15; rows vc, vc+16, vc+32, vc+48
  const int vch = t & 15;
  // (vc+16k)&7 == vc&7, so the LDS XOR-swizzle term is row-batch invariant
  const int vswz = (vch * 8) ^ ((vc & 7) * 8);

  // per-lane mask row bases: rows i0 + rbase + mt*16 + m  (L2-hot)
  const unsigned char* mrow = maskb + (size_t)(i0 + rbase + m) * NDIM + quad * 8;

#define PREFETCH(js_)                                                          \
  {                                                                            \
    pv0 = vsrc[(size_t)(bt * 64 + vc     ) * 64 + (js_) * 16 + vch];           \
    pv1 = vsrc[(size_t)(bt * 64 + vc + 16) * 64 + (js_) * 16 + vch];           \
    pv2 = vsrc[(size_t)(bt * 64 + vc + 32) * 64 + (js_) * 16 + vch];           \
    pv3 = vsrc[(size_t)(bt * 64 + vc + 48) * 64 + (js_) * 16 + vch];           \
  }

  PREFETCH(0);

#pragma unroll
  for (int js = 0; js < 4; ++js) {
    __syncthreads();   // prev quarter fully consumed
    // commit prefetched VT quarter to LDS (swizzled 16B chunks)
    *(uint4*)&sm.u.s.vt[vc     ][vswz] = pv0;
    *(uint4*)&sm.u.s.vt[vc + 16][vswz] = pv1;
    *(uint4*)&sm.u.s.vt[vc + 32][vswz] = pv2;
    *(uint4*)&sm.u.s.vt[vc + 48][vswz] = pv3;
    __syncthreads();
    if (js < 3) PREFETCH(js + 1);   // latency hides under this quarter's compute

    // mask bytes for this quarter: 16 x uint2 per lane, issued together
    uint2 mk[4][4];
#pragma unroll
    for (int mt = 0; mt < 4; ++mt) {
      const unsigned char* mbp = mrow + (size_t)(mt * 16) * NDIM + js * 128;
#pragma unroll
      for (int ksl = 0; ksl < 4; ++ksl)
        mk[mt][ksl] = *(const uint2*)(mbp + ksl * 32);
    }

#pragma unroll
    for (int ksl = 0; ksl < 4; ++ksl) {
      int jq = ksl * 32 + quad * 8;   // j within quarter
      half8v F8 = *(const half8v*)&sm.sF16[h][js * 128 + jq];
      half8v P8 = *(const half8v*)&sm.sP16[h][js * 128 + jq];
      int vbase = (h * 32 + m) * 128 + (jq ^ ((m & 7) * 8));
      half8v b0 = *(const half8v*)&sm.u.s.vt[0][vbase];
      half8v b1 = *(const half8v*)&sm.u.s.vt[0][vbase + 16 * 128];
      uint4 fu = __builtin_bit_cast(uint4, F8);
      uint4 pu = __builtin_bit_cast(uint4, P8);
      half2v f2a = __builtin_bit_cast(half2v, fu.x), f2b = __builtin_bit_cast(half2v, fu.y);
      half2v f2c = __builtin_bit_cast(half2v, fu.z), f2d = __builtin_bit_cast(half2v, fu.w);
      half2v p2a = __builtin_bit_cast(half2v, pu.x), p2b = __builtin_bit_cast(half2v, pu.y);
      half2v p2c = __builtin_bit_cast(half2v, pu.z), p2d = __builtin_bit_cast(half2v, pu.w);
#pragma unroll
      for (int mt = 0; mt < 4; ++mt) {
        unsigned mw0 = mk[mt][ksl].x, mw1 = mk[mt][ksl].y;
        uint4 eu;
        eu.x = __builtin_bit_cast(unsigned,
                 __builtin_elementwise_max(e2[mt] * f2a, q2[mt] * p2a)) &
               __builtin_amdgcn_perm(0u, mw0, 0x01010000u);
        eu.y = __builtin_bit_cast(unsigned,
                 __builtin_elementwise_max(e2[mt] * f2b, q2[mt] * p2b)) &
               __builtin_amdgcn_perm(0u, mw0, 0x03030202u);
        eu.z = __builtin_bit_cast(unsigned,
                 __builtin_elementwise_max(e2[mt] * f2c, q2[mt] * p2c)) &
               __builtin_amdgcn_perm(0u, mw1, 0x01010000u);
        eu.w = __builtin_bit_cast(unsigned,
                 __builtin_elementwise_max(e2[mt] * f2d, q2[mt] * p2d)) &
               __builtin_amdgcn_perm(0u, mw1, 0x03030202u);
        half8v af = __builtin_bit_cast(half8v, eu);
        acc[mt][0] = __builtin_amdgcn_mfma_f32_16x16x32_f16(af, b0,    acc[mt][0], 0, 0, 0);
        acc[mt][1] = __builtin_amdgcn_mfma_f32_16x16x32_f16(af, b1,    acc[mt][1], 0, 0, 0);
        accs[mt]   = __builtin_amdgcn_mfma_f32_16x16x32_f16(af, bones, accs[mt],   0, 0, 0);
      }
    }
  }
#undef PREFETCH

  __syncthreads();   // vt dead -> otile overlay
  // normalize by row sums (same C-layout row as acc -> no shuffle needed)
#pragma unroll
  for (int mt = 0; mt < 4; ++mt)
#pragma unroll
    for (int r = 0; r < 4; ++r) {
      float sc = __builtin_amdgcn_rcpf(accs[mt][r]);
      int i_loc = rbase + mt * 16 + quad * 4 + r;
#pragma unroll
      for (int nt = 0; nt < 2; ++nt)
        sm.u.e.otile[i_loc][h * 32 + nt * 16 + m] = acc[mt][nt][r] * sc;
    }
  __syncthreads();

  // LayerNorm over C=64 per row (128 rows, 2 threads/row x 32 ch)
  {
    int i = t & 127, cg = t >> 7;
    float s1 = 0.f, s2 = 0.f;
#pragma unroll
    for (int cc = 0; cc < 32; ++cc) {
      float v = sm.u.e.otile[i][cg * 32 + cc];
      s1 += v; s2 += v * v;
    }
    sm.u.e.rsum[cg][i] = s1;
    sm.u.e.rsq[cg][i]  = s2;
  }
  __syncthreads();
  if (t < 128) {
    int i = t;
    float s1 = sm.u.e.rsum[0][i] + sm.u.e.rsum[1][i];
    float s2 = sm.u.e.rsq[0][i]  + sm.u.e.rsq[1][i];
    float mu  = s1 * (1.f / 64.f);
    float var = s2 * (1.f / 64.f) - mu * mu;
    sm.u.e.mu[i] = mu;
    sm.u.e.rs[i] = rsqrtf(var + 1e-5f);
  }
  __syncthreads();
  {
    int i = t & 127, cg = t >> 7;
    float mu = sm.u.e.mu[i], rs = sm.u.e.rs[i];
    int n = i0 + i;
#pragma unroll
    for (int cc = 0; cc < 32; ++cc) {
      int c = cg * 32 + cc;
      float v = (sm.u.e.otile[i][c] - mu) * rs * gamma[c] + beta[c];
      out[((size_t)(b * CDIM + c) * TDIM + tt) * NDIM + n] = v;
    }
  }
}

// ---------------------------------------------------------------------------
extern "C" void kernel_launch(void* const* d_in, const int* in_sizes, int n_in,
                              void* d_out, int out_size, void* d_ws, size_t ws_size,
                              hipStream_t stream) {
  const float* x     = (const float*)d_in[0];
  const int*   gso   = (const int*)d_in[1];
  const float* Wq    = (const float*)d_in[2];
  const float* Wk    = (const float*)d_in[3];
  const float* Wv    = (const float*)d_in[4];
  const float* a_src = (const float*)d_in[5];
  const float* a_dst = (const float*)d_in[6];
  const float* gamma = (const float*)d_in[7];
  const float* beta  = (const float*)d_in[8];
  float* out = (float*)d_out;

  char* ws = (char*)d_ws;
  _Float16* VT_g  = (_Float16*)ws;
  float*    s_src = (float*)(ws + 12582912);
  float*    s_dst = (float*)(ws + 13369344);
  unsigned char* maskb = (unsigned char*)(ws + 14155776);

  k1_v<<<832, 256, 0, stream>>>(x, Wv, Wq, Wk, a_src, a_dst, gso,
                                VT_g, s_src, s_dst, maskb);
  k2_attn<<<768, 256, 0, stream>>>(VT_g, s_src, s_dst, maskb, gamma, beta, out);
}